// Round 4
// baseline (896.391 us; speedup 1.0000x reference)
//
#include <hip/hip_runtime.h>
#include <hip/hip_bf16.h>

#define N_NODES 100000
#define N_EDGES 1600000
#define IN_DIM 128
#define HID 32
#define BW 128                                   // bucket width (dst nodes)
#define NBUCK ((N_NODES + BW - 1) / BW)          // 782

// ======================= Layer-1 GEMM: h1 = x@W1, el1, er1 ============================
// Also zeroes bucket_cnt[] (ws is poisoned 0xAA each call) for the bucket histogram.
__global__ __launch_bounds__(256) void gemm1_kernel(
    const float* __restrict__ x, const float* __restrict__ W,
    const float* __restrict__ al, const float* __restrict__ ar,
    float* __restrict__ h, float* __restrict__ el, float* __restrict__ er,
    int* __restrict__ bucket_cnt)
{
    __shared__ float Ws[IN_DIM][HID];   // 16 KB
    __shared__ float Xs[8][IN_DIM];     // 4 KB
    const int tid = threadIdx.x;
    const int row0 = blockIdx.x * 8;

    const int gid = blockIdx.x * 256 + tid;
    if (gid < NBUCK) bucket_cnt[gid] = 0;

    {   // stage W1 (4096 floats)
        const float4* W4 = (const float4*)W;
        float4* Ws4 = (float4*)&Ws[0][0];
        #pragma unroll
        for (int i = 0; i < 4; ++i) Ws4[tid + 256 * i] = W4[tid + 256 * i];
    }
    {   // stage 8 rows of x
        const float4* X4 = (const float4*)(x + (size_t)row0 * IN_DIM);
        ((float4*)&Xs[0][0])[tid] = X4[tid];
    }
    __syncthreads();

    const int r = tid >> 5, col = tid & 31;
    const int row = row0 + r;
    float acc = 0.f;
    #pragma unroll
    for (int k = 0; k < IN_DIM; k += 4) {
        float4 xv = *(const float4*)&Xs[r][k];
        acc += xv.x * Ws[k][col] + xv.y * Ws[k + 1][col]
             + xv.z * Ws[k + 2][col] + xv.w * Ws[k + 3][col];
    }
    h[(size_t)row * HID + col] = acc;

    float elp = acc * al[col];
    float erp = acc * ar[col];
    #pragma unroll
    for (int m = 16; m > 0; m >>= 1) {
        elp += __shfl_xor(elp, m, 32);
        erp += __shfl_xor(erp, m, 32);
    }
    if (col == 0) { el[row] = elp; er[row] = erp; }
}

// ======================= Bucket histogram =============================================
// 16 edges/thread, LDS-aggregated; ~270k no-return global atomics total.
__global__ __launch_bounds__(256) void bhist_kernel(const int* __restrict__ dst,
                                                    int* __restrict__ bucket_cnt)
{
    __shared__ int hist[NBUCK];
    const int tid = threadIdx.x;
    for (int i = tid; i < NBUCK; i += 256) hist[i] = 0;
    __syncthreads();
    const int t = blockIdx.x * 256 + tid;         // 16-edge group id
    if (t < N_EDGES / 16) {
        const int4* d4 = (const int4*)dst + (size_t)t * 4;
        #pragma unroll
        for (int q = 0; q < 4; ++q) {
            const int4 d = d4[q];
            atomicAdd(&hist[d.x >> 7], 1); atomicAdd(&hist[d.y >> 7], 1);
            atomicAdd(&hist[d.z >> 7], 1); atomicAdd(&hist[d.w >> 7], 1);
        }
    }
    __syncthreads();
    for (int i = tid; i < NBUCK; i += 256) {
        const int hv = hist[i];
        if (hv) atomicAdd(&bucket_cnt[i], hv);
    }
}

// ======================= Bucket scan (1 block) ========================================
__global__ __launch_bounds__(1024) void bscan_kernel(const int* __restrict__ cnt,
                                                     int* __restrict__ base,
                                                     int* __restrict__ gcur)
{
    const int t = threadIdx.x;
    const int v = (t < NBUCK) ? cnt[t] : 0;
    const int lane = t & 63, wid = t >> 6;        // 16 waves
    int pre = v;
    #pragma unroll
    for (int off = 1; off < 64; off <<= 1) {
        const int n = __shfl_up(pre, off, 64);
        if (lane >= off) pre += n;
    }
    __shared__ int ws[16];
    if (lane == 63) ws[wid] = pre;
    __syncthreads();
    int wo = 0;
    for (int k = 0; k < wid; ++k) wo += ws[k];
    const int ex = wo + pre - v;                  // exclusive prefix
    if (t < NBUCK) { base[t] = ex; gcur[t] = ex; }
}

// ======================= Binning (block-aggregated multisplit) ========================
// Tile 4096 edges/block: LDS hist -> one global atomic per (block,bucket) reserves a
// contiguous range -> LDS-cursor append. Writes per (block,bucket) are consecutive, so
// lines fill while L2-resident (kills the 107MB random-line write traffic of round 3).
__global__ __launch_bounds__(256) void bin_kernel(const int* __restrict__ src,
                                                  const int* __restrict__ dst,
                                                  int* __restrict__ gcur,
                                                  int2* __restrict__ pairs)
{
    __shared__ int hist[NBUCK];
    __shared__ int cur[NBUCK];
    const int tid = threadIdx.x;
    for (int i = tid; i < NBUCK; i += 256) hist[i] = 0;
    __syncthreads();

    const int t = blockIdx.x * 256 + tid;         // 16-edge group id
    const bool act = t < N_EDGES / 16;
    int4 sv[4], dv[4];
    if (act) {
        const int4* s4 = (const int4*)src + (size_t)t * 4;
        const int4* d4 = (const int4*)dst + (size_t)t * 4;
        #pragma unroll
        for (int q = 0; q < 4; ++q) { sv[q] = s4[q]; dv[q] = d4[q]; }
        #pragma unroll
        for (int q = 0; q < 4; ++q) {
            atomicAdd(&hist[dv[q].x >> 7], 1); atomicAdd(&hist[dv[q].y >> 7], 1);
            atomicAdd(&hist[dv[q].z >> 7], 1); atomicAdd(&hist[dv[q].w >> 7], 1);
        }
    }
    __syncthreads();
    for (int i = tid; i < NBUCK; i += 256) {
        const int hv = hist[i];
        cur[i] = hv ? atomicAdd(&gcur[i], hv) : 0;
    }
    __syncthreads();
    if (act) {
        #pragma unroll
        for (int q = 0; q < 4; ++q) {
            const int ss[4] = {sv[q].x, sv[q].y, sv[q].z, sv[q].w};
            const int dd[4] = {dv[q].x, dv[q].y, dv[q].z, dv[q].w};
            #pragma unroll
            for (int r = 0; r < 4; ++r) {
                const int slot = atomicAdd(&cur[dd[r] >> 7], 1);
                pairs[slot] = make_int2(ss[r], dd[r]);
            }
        }
    }
}

// ======================= Bucket gather (both layers) ==================================
// One workgroup per bucket: LDS accumulators accum[BW][HID] + den[BW]; stream the
// bucket's (src,dst) pairs sequentially; ds_add_f32 accumulate (col==bank, clean);
// epilogue writes finished activations sequentially.
// MODE 0: out = elu(num/den + b)   MODE 1: out = num/den + b
template <int MODE>
__global__ __launch_bounds__(512) void bgather_kernel(
    const int* __restrict__ bucket_base, const int* __restrict__ bucket_cnt,
    const int2* __restrict__ pairs,
    const float* __restrict__ el, const float* __restrict__ er,
    const float* __restrict__ h, const float* __restrict__ bias,
    float* __restrict__ out)
{
    __shared__ float accum[BW][HID];   // 16 KB
    __shared__ float den[BW];
    const int tid = threadIdx.x;
    const int b = blockIdx.x;
    {
        float* a = &accum[0][0];
        for (int i = tid; i < BW * HID; i += 512) a[i] = 0.f;
        if (tid < BW) den[tid] = 0.f;
    }
    __syncthreads();

    const int ebase = bucket_base[b];
    const int ecnt  = bucket_cnt[b];
    const int slot = tid >> 5;         // 0..15 edge slots
    const int col  = tid & 31;
    const int node0 = b * BW;

    int j = slot;
    for (; j + 16 < ecnt; j += 32) {
        const int2 pA = pairs[ebase + j];
        const int2 pB = pairs[ebase + j + 16];
        float scA = el[pA.x] + er[pA.y];
        float scB = el[pB.x] + er[pB.y];
        const float hA = h[(size_t)pA.x * HID + col];
        const float hB = h[(size_t)pB.x * HID + col];
        scA = scA > 0.f ? scA : 0.2f * scA;
        scB = scB > 0.f ? scB : 0.2f * scB;
        const float wA = __expf(scA);
        const float wB = __expf(scB);
        atomicAdd(&accum[pA.y - node0][col], wA * hA);
        atomicAdd(&accum[pB.y - node0][col], wB * hB);
        if (col == 0) {
            atomicAdd(&den[pA.y - node0], wA);
            atomicAdd(&den[pB.y - node0], wB);
        }
    }
    if (j < ecnt) {
        const int2 p = pairs[ebase + j];
        float sc = el[p.x] + er[p.y];
        const float hv = h[(size_t)p.x * HID + col];
        sc = sc > 0.f ? sc : 0.2f * sc;
        const float w = __expf(sc);
        atomicAdd(&accum[p.y - node0][col], w * hv);
        if (col == 0) atomicAdd(&den[p.y - node0], w);
    }
    __syncthreads();

    const int nn = min(BW, N_NODES - node0);
    for (int i = tid; i < nn * HID; i += 512) {
        const int ln = i >> 5, c = i & 31;
        const float d = den[ln];
        float v = d > 0.f ? accum[ln][c] / d : 0.f;
        v += bias[c];
        if (MODE == 0) v = v > 0.f ? v : expm1f(v);   // ELU
        out[(size_t)(node0 + ln) * HID + c] = v;
    }
}

// ======================= Layer-2 GEMM: h2 = x2@W2, el2, er2 ===========================
__global__ __launch_bounds__(256) void gemm2_kernel(
    const float* __restrict__ x2, const float* __restrict__ W,
    const float* __restrict__ al, const float* __restrict__ ar,
    float* __restrict__ h, float* __restrict__ el, float* __restrict__ er)
{
    __shared__ float Ws[HID][HID];  // 4 KB
    __shared__ float Xs[8][HID];    // 1 KB
    const int tid = threadIdx.x;
    const int row0 = blockIdx.x * 8;
    const int r = tid >> 5, c = tid & 31;
    const int row = row0 + r;

    ((float4*)&Ws[0][0])[tid] = ((const float4*)W)[tid];
    Xs[r][c] = x2[(size_t)row * HID + c];
    __syncthreads();

    float acc = 0.f;
    #pragma unroll
    for (int k = 0; k < HID; ++k) acc += Xs[r][k] * Ws[k][c];
    h[(size_t)row * HID + c] = acc;

    float elp = acc * al[c];
    float erp = acc * ar[c];
    #pragma unroll
    for (int m = 16; m > 0; m >>= 1) {
        elp += __shfl_xor(elp, m, 32);
        erp += __shfl_xor(erp, m, 32);
    }
    if (c == 0) { el[row] = elp; er[row] = erp; }
}

extern "C" void kernel_launch(void* const* d_in, const int* in_sizes, int n_in,
                              void* d_out, int out_size, void* d_ws, size_t ws_size,
                              hipStream_t stream) {
    const float* features = (const float*)d_in[0];
    const int*   src      = (const int*)d_in[1];
    const int*   dst      = (const int*)d_in[2];
    const float* W1       = (const float*)d_in[3];
    const float* al1      = (const float*)d_in[4];
    const float* ar1      = (const float*)d_in[5];
    const float* b1       = (const float*)d_in[6];
    const float* W2       = (const float*)d_in[7];
    const float* al2      = (const float*)d_in[8];
    const float* ar2      = (const float*)d_in[9];
    const float* b2       = (const float*)d_in[10];
    float* out = (float*)d_out;

    // Workspace layout (~39 MB). h2/el2/er2 alias h1/el1/er1 (dead after gather1).
    int*  bucket_cnt  = (int*)d_ws;                    // 784
    int*  bucket_base = bucket_cnt + 784;              // 784
    int*  gcur        = bucket_base + 784;             // 784
    int2* pairs       = (int2*)(gcur + 784);           // 1.6M int2 (12.8 MB)
    float* h1  = (float*)(pairs + N_EDGES);            // 12.8 MB
    float* el1 = h1 + (size_t)N_NODES * HID;
    float* er1 = el1 + N_NODES;
    float* x2  = er1 + N_NODES;                        // 12.8 MB

    const int NB_E16 = (N_EDGES / 16 + 255) / 256;     // 391

    // Layer-1 GEMM (+ zero bucket_cnt)
    gemm1_kernel<<<N_NODES / 8, 256, 0, stream>>>(features, W1, al1, ar1,
                                                  h1, el1, er1, bucket_cnt);
    // Bucket CSR build
    bhist_kernel<<<NB_E16, 256, 0, stream>>>(dst, bucket_cnt);
    bscan_kernel<<<1, 1024, 0, stream>>>(bucket_cnt, bucket_base, gcur);
    bin_kernel<<<NB_E16, 256, 0, stream>>>(src, dst, gcur, pairs);
    // Layer-1 aggregate -> x2 = elu(num/den + b1)
    bgather_kernel<0><<<NBUCK, 512, 0, stream>>>(bucket_base, bucket_cnt, pairs,
                                                 el1, er1, h1, b1, x2);
    // Layer-2 GEMM (outputs alias layer-1 buffers)
    gemm2_kernel<<<N_NODES / 8, 256, 0, stream>>>(x2, W2, al2, ar2, h1, el1, er1);
    // Layer-2 aggregate -> out = num/den + b2
    bgather_kernel<1><<<NBUCK, 512, 0, stream>>>(bucket_base, bucket_cnt, pairs,
                                                 el1, er1, h1, b2, out);
}

// Round 5
// 323.657 us; speedup vs baseline: 2.7696x; 2.7696x over previous
//
#include <hip/hip_runtime.h>
#include <hip/hip_bf16.h>

#define N_NODES 100000
#define N_EDGES 1600000
#define IN_DIM 128
#define HID 32
#define BW 128                                   // bucket width (dst nodes)
#define NBUCK ((N_NODES + BW - 1) / BW)          // 782

// ======================= Layer-1 GEMM: h1 = x@W1, el1, er1 ============================
// Also zeroes bucket_cnt[] (ws is poisoned 0xAA each call) for the bucket histogram.
__global__ __launch_bounds__(256) void gemm1_kernel(
    const float* __restrict__ x, const float* __restrict__ W,
    const float* __restrict__ al, const float* __restrict__ ar,
    float* __restrict__ h, float* __restrict__ el, float* __restrict__ er,
    int* __restrict__ bucket_cnt)
{
    __shared__ float Ws[IN_DIM][HID];   // 16 KB
    __shared__ float Xs[8][IN_DIM];     // 4 KB
    const int tid = threadIdx.x;
    const int row0 = blockIdx.x * 8;

    const int gid = blockIdx.x * 256 + tid;
    if (gid < NBUCK) bucket_cnt[gid] = 0;

    {   // stage W1 (4096 floats)
        const float4* W4 = (const float4*)W;
        float4* Ws4 = (float4*)&Ws[0][0];
        #pragma unroll
        for (int i = 0; i < 4; ++i) Ws4[tid + 256 * i] = W4[tid + 256 * i];
    }
    {   // stage 8 rows of x
        const float4* X4 = (const float4*)(x + (size_t)row0 * IN_DIM);
        ((float4*)&Xs[0][0])[tid] = X4[tid];
    }
    __syncthreads();

    const int r = tid >> 5, col = tid & 31;
    const int row = row0 + r;
    float acc = 0.f;
    #pragma unroll
    for (int k = 0; k < IN_DIM; k += 4) {
        float4 xv = *(const float4*)&Xs[r][k];
        acc += xv.x * Ws[k][col] + xv.y * Ws[k + 1][col]
             + xv.z * Ws[k + 2][col] + xv.w * Ws[k + 3][col];
    }
    h[(size_t)row * HID + col] = acc;

    float elp = acc * al[col];
    float erp = acc * ar[col];
    #pragma unroll
    for (int m = 16; m > 0; m >>= 1) {
        elp += __shfl_xor(elp, m, 32);
        erp += __shfl_xor(erp, m, 32);
    }
    if (col == 0) { el[row] = elp; er[row] = erp; }
}

// ======================= Bucket histogram =============================================
__global__ __launch_bounds__(256) void bhist_kernel(const int* __restrict__ dst,
                                                    int* __restrict__ bucket_cnt)
{
    __shared__ int hist[NBUCK];
    const int tid = threadIdx.x;
    for (int i = tid; i < NBUCK; i += 256) hist[i] = 0;
    __syncthreads();
    const int t = blockIdx.x * 256 + tid;         // 16-edge group id
    if (t < N_EDGES / 16) {
        const int4* d4 = (const int4*)dst + (size_t)t * 4;
        #pragma unroll
        for (int q = 0; q < 4; ++q) {
            const int4 d = d4[q];
            atomicAdd(&hist[d.x >> 7], 1); atomicAdd(&hist[d.y >> 7], 1);
            atomicAdd(&hist[d.z >> 7], 1); atomicAdd(&hist[d.w >> 7], 1);
        }
    }
    __syncthreads();
    for (int i = tid; i < NBUCK; i += 256) {
        const int hv = hist[i];
        if (hv) atomicAdd(&bucket_cnt[i], hv);
    }
}

// ======================= Bucket scan (1 block) ========================================
__global__ __launch_bounds__(1024) void bscan_kernel(const int* __restrict__ cnt,
                                                     int* __restrict__ base,
                                                     int* __restrict__ gcur)
{
    const int t = threadIdx.x;
    const int v = (t < NBUCK) ? cnt[t] : 0;
    const int lane = t & 63, wid = t >> 6;        // 16 waves
    int pre = v;
    #pragma unroll
    for (int off = 1; off < 64; off <<= 1) {
        const int n = __shfl_up(pre, off, 64);
        if (lane >= off) pre += n;
    }
    __shared__ int ws[16];
    if (lane == 63) ws[wid] = pre;
    __syncthreads();
    int wo = 0;
    for (int k = 0; k < wid; ++k) wo += ws[k];
    const int ex = wo + pre - v;                  // exclusive prefix
    if (t < NBUCK) { base[t] = ex; gcur[t] = ex; }
}

// ======================= Binning (block-aggregated multisplit) ========================
__global__ __launch_bounds__(256) void bin_kernel(const int* __restrict__ src,
                                                  const int* __restrict__ dst,
                                                  int* __restrict__ gcur,
                                                  int2* __restrict__ pairs)
{
    __shared__ int hist[NBUCK];
    __shared__ int cur[NBUCK];
    const int tid = threadIdx.x;
    for (int i = tid; i < NBUCK; i += 256) hist[i] = 0;
    __syncthreads();

    const int t = blockIdx.x * 256 + tid;         // 16-edge group id
    const bool act = t < N_EDGES / 16;
    int4 sv[4], dv[4];
    if (act) {
        const int4* s4 = (const int4*)src + (size_t)t * 4;
        const int4* d4 = (const int4*)dst + (size_t)t * 4;
        #pragma unroll
        for (int q = 0; q < 4; ++q) { sv[q] = s4[q]; dv[q] = d4[q]; }
        #pragma unroll
        for (int q = 0; q < 4; ++q) {
            atomicAdd(&hist[dv[q].x >> 7], 1); atomicAdd(&hist[dv[q].y >> 7], 1);
            atomicAdd(&hist[dv[q].z >> 7], 1); atomicAdd(&hist[dv[q].w >> 7], 1);
        }
    }
    __syncthreads();
    for (int i = tid; i < NBUCK; i += 256) {
        const int hv = hist[i];
        cur[i] = hv ? atomicAdd(&gcur[i], hv) : 0;
    }
    __syncthreads();
    if (act) {
        #pragma unroll
        for (int q = 0; q < 4; ++q) {
            const int ss[4] = {sv[q].x, sv[q].y, sv[q].z, sv[q].w};
            const int dd[4] = {dv[q].x, dv[q].y, dv[q].z, dv[q].w};
            #pragma unroll
            for (int r = 0; r < 4; ++r) {
                const int slot = atomicAdd(&cur[dd[r] >> 7], 1);
                pairs[slot] = make_int2(ss[r], dd[r]);
            }
        }
    }
}

// ======================= Bucket-local sort -> node-level CSR ==========================
// One block per bucket. Scatter targets span only this bucket's contiguous csr range
// (~8 KB, L2-resident), so lines fill before eviction — unlike round-3's global
// scatter which paid one full HBM line per 4B store (107 MB).
__global__ __launch_bounds__(256) void lsort_kernel(
    const int* __restrict__ bucket_base, const int* __restrict__ bucket_cnt,
    const int2* __restrict__ pairs,
    int* __restrict__ deg, int* __restrict__ rowptr, int* __restrict__ csr_src)
{
    __shared__ int lhist[BW];
    __shared__ int lcur[BW];
    __shared__ int w0tot;
    const int tid = threadIdx.x;
    const int b = blockIdx.x;
    if (tid < BW) lhist[tid] = 0;
    __syncthreads();
    const int ebase = bucket_base[b];
    const int ecnt  = bucket_cnt[b];
    for (int i = tid; i < ecnt; i += 256)
        atomicAdd(&lhist[pairs[ebase + i].y & (BW - 1)], 1);
    __syncthreads();
    // exclusive scan of the 128 local degrees (2 waves)
    const int lane = tid & 63;
    int v = 0;
    if (tid < BW) v = lhist[tid];
    int pre = v;
    #pragma unroll
    for (int off = 1; off < 64; off <<= 1) {
        const int n = __shfl_up(pre, off, 64);
        if (lane >= off) pre += n;
    }
    if (tid == 63) w0tot = pre;
    __syncthreads();
    if (tid < BW) {
        const int ex = pre - v + (tid >= 64 ? w0tot : 0);
        lcur[tid] = ex;
        const int node = b * BW + tid;
        if (node < N_NODES) { deg[node] = v; rowptr[node] = ebase + ex; }
    }
    __syncthreads();
    for (int i = tid; i < ecnt; i += 256) {
        const int2 p = pairs[ebase + i];
        const int slot = atomicAdd(&lcur[p.y & (BW - 1)], 1);
        csr_src[ebase + slot] = p.x;
    }
}

// ======================= Gather-aggregate (both layers) ===============================
// One wave64 per dst node: lanes = (e2, col); register accumulation; 4-deep unroll
// gives 4 independent csr->el/h load chains per half-wave for MLP.
// MODE 0: out = elu(num/den + b)   MODE 1: out = num/den + b
template <int MODE>
__global__ __launch_bounds__(256) void gather_kernel(
    const int* __restrict__ rowptr, const int* __restrict__ deg,
    const int* __restrict__ csr_src,
    const float* __restrict__ el, const float* __restrict__ er,
    const float* __restrict__ h, const float* __restrict__ bias,
    float* __restrict__ out)
{
    const int tid = threadIdx.x;
    const int node = blockIdx.x * 4 + (tid >> 6);    // grid = N/4 exactly
    const int e2 = (tid >> 5) & 1, col = tid & 31;
    const int cnt = deg[node];
    const int start = rowptr[node];
    const float erd = er[node];
    float acc = 0.f, den = 0.f;
    int j = e2;
    for (; j + 6 < cnt; j += 8) {
        const int s0 = csr_src[start + j];
        const int s1 = csr_src[start + j + 2];
        const int s2 = csr_src[start + j + 4];
        const int s3 = csr_src[start + j + 6];
        float c0 = el[s0] + erd;
        float c1 = el[s1] + erd;
        float c2 = el[s2] + erd;
        float c3 = el[s3] + erd;
        const float h0 = h[(size_t)s0 * HID + col];
        const float h1v = h[(size_t)s1 * HID + col];
        const float h2v = h[(size_t)s2 * HID + col];
        const float h3v = h[(size_t)s3 * HID + col];
        c0 = c0 > 0.f ? c0 : 0.2f * c0;
        c1 = c1 > 0.f ? c1 : 0.2f * c1;
        c2 = c2 > 0.f ? c2 : 0.2f * c2;
        c3 = c3 > 0.f ? c3 : 0.2f * c3;
        const float w0 = __expf(c0);
        const float w1 = __expf(c1);
        const float w2 = __expf(c2);
        const float w3 = __expf(c3);
        den += (w0 + w1) + (w2 + w3);
        acc += w0 * h0 + w1 * h1v + w2 * h2v + w3 * h3v;
    }
    for (; j < cnt; j += 2) {
        const int s = csr_src[start + j];
        float sc = el[s] + erd;
        sc = sc > 0.f ? sc : 0.2f * sc;
        const float w = __expf(sc);
        den += w;
        acc += w * h[(size_t)s * HID + col];
    }
    acc += __shfl_xor(acc, 32, 64);
    den += __shfl_xor(den, 32, 64);
    if (e2 == 0) {
        float v = den > 0.f ? acc / den : 0.f;
        v += bias[col];
        if (MODE == 0) v = v > 0.f ? v : expm1f(v);  // ELU
        out[(size_t)node * HID + col] = v;
    }
}

// ======================= Layer-2 GEMM: h2 = x2@W2, el2, er2 ===========================
__global__ __launch_bounds__(256) void gemm2_kernel(
    const float* __restrict__ x2, const float* __restrict__ W,
    const float* __restrict__ al, const float* __restrict__ ar,
    float* __restrict__ h, float* __restrict__ el, float* __restrict__ er)
{
    __shared__ float Ws[HID][HID];  // 4 KB
    __shared__ float Xs[8][HID];    // 1 KB
    const int tid = threadIdx.x;
    const int row0 = blockIdx.x * 8;
    const int r = tid >> 5, c = tid & 31;
    const int row = row0 + r;

    ((float4*)&Ws[0][0])[tid] = ((const float4*)W)[tid];
    Xs[r][c] = x2[(size_t)row * HID + c];
    __syncthreads();

    float acc = 0.f;
    #pragma unroll
    for (int k = 0; k < HID; ++k) acc += Xs[r][k] * Ws[k][c];
    h[(size_t)row * HID + c] = acc;

    float elp = acc * al[c];
    float erp = acc * ar[c];
    #pragma unroll
    for (int m = 16; m > 0; m >>= 1) {
        elp += __shfl_xor(elp, m, 32);
        erp += __shfl_xor(erp, m, 32);
    }
    if (c == 0) { el[row] = elp; er[row] = erp; }
}

extern "C" void kernel_launch(void* const* d_in, const int* in_sizes, int n_in,
                              void* d_out, int out_size, void* d_ws, size_t ws_size,
                              hipStream_t stream) {
    const float* features = (const float*)d_in[0];
    const int*   src      = (const int*)d_in[1];
    const int*   dst      = (const int*)d_in[2];
    const float* W1       = (const float*)d_in[3];
    const float* al1      = (const float*)d_in[4];
    const float* ar1      = (const float*)d_in[5];
    const float* b1       = (const float*)d_in[6];
    const float* W2       = (const float*)d_in[7];
    const float* al2      = (const float*)d_in[8];
    const float* ar2      = (const float*)d_in[9];
    const float* b2       = (const float*)d_in[10];
    float* out = (float*)d_out;

    // Workspace (~47 MB). h2/el2/er2 alias h1/el1/er1 (dead after gather1).
    int*  bucket_cnt  = (int*)d_ws;                    // 784
    int*  bucket_base = bucket_cnt + 784;              // 784
    int*  gcur        = bucket_base + 784;             // 784
    int*  deg         = gcur + 784;                    // 100k
    int*  rowptr      = deg + N_NODES;                 // 100k
    int*  csr_src     = rowptr + N_NODES;              // 1.6M (6.4 MB)
    int2* pairs       = (int2*)(csr_src + N_EDGES);    // 1.6M int2 (12.8 MB)
    float* h1  = (float*)(pairs + N_EDGES);            // 12.8 MB
    float* el1 = h1 + (size_t)N_NODES * HID;
    float* er1 = el1 + N_NODES;
    float* x2  = er1 + N_NODES;                        // 12.8 MB

    const int NB_E16 = (N_EDGES / 16 + 255) / 256;     // 391

    // Layer-1 GEMM (+ zero bucket_cnt)
    gemm1_kernel<<<N_NODES / 8, 256, 0, stream>>>(features, W1, al1, ar1,
                                                  h1, el1, er1, bucket_cnt);
    // Bucket CSR build: hist -> scan -> bin -> bucket-local sort to node CSR
    bhist_kernel<<<NB_E16, 256, 0, stream>>>(dst, bucket_cnt);
    bscan_kernel<<<1, 1024, 0, stream>>>(bucket_cnt, bucket_base, gcur);
    bin_kernel<<<NB_E16, 256, 0, stream>>>(src, dst, gcur, pairs);
    lsort_kernel<<<NBUCK, 256, 0, stream>>>(bucket_base, bucket_cnt, pairs,
                                            deg, rowptr, csr_src);
    // Layer-1 aggregate -> x2 = elu(num/den + b1)
    gather_kernel<0><<<N_NODES / 4, 256, 0, stream>>>(rowptr, deg, csr_src,
                                                      el1, er1, h1, b1, x2);
    // Layer-2 GEMM (outputs alias layer-1 buffers)
    gemm2_kernel<<<N_NODES / 8, 256, 0, stream>>>(x2, W2, al2, ar2, h1, el1, er1);
    // Layer-2 aggregate -> out = num/den + b2
    gather_kernel<1><<<N_NODES / 4, 256, 0, stream>>>(rowptr, deg, csr_src,
                                                      el1, er1, h1, b2, out);
}

// Round 6
// 312.635 us; speedup vs baseline: 2.8672x; 1.0353x over previous
//
#include <hip/hip_runtime.h>
#include <hip/hip_bf16.h>

#define N_NODES 100000
#define N_EDGES 1600000
#define IN_DIM 128
#define HID 32
#define BW 128                                   // bucket width (dst nodes)
#define NBUCK ((N_NODES + BW - 1) / BW)          // 782

// Packed edge: (src << 7) | local_dst.  src < 2^17, local_dst < 128.

// ======================= Layer-1 GEMM: h1(bf16) = x@W1, el1, er1 ======================
// Also zeroes bucket_cnt[] (ws is poisoned 0xAA each call).
__global__ __launch_bounds__(256) void gemm1_kernel(
    const float* __restrict__ x, const float* __restrict__ W,
    const float* __restrict__ al, const float* __restrict__ ar,
    __hip_bfloat16* __restrict__ h, float* __restrict__ el, float* __restrict__ er,
    int* __restrict__ bucket_cnt)
{
    __shared__ float Ws[IN_DIM][HID];   // 16 KB
    __shared__ float Xs[8][IN_DIM];     // 4 KB
    const int tid = threadIdx.x;
    const int row0 = blockIdx.x * 8;

    const int gid = blockIdx.x * 256 + tid;
    if (gid < NBUCK) bucket_cnt[gid] = 0;

    {   // stage W1 (4096 floats)
        const float4* W4 = (const float4*)W;
        float4* Ws4 = (float4*)&Ws[0][0];
        #pragma unroll
        for (int i = 0; i < 4; ++i) Ws4[tid + 256 * i] = W4[tid + 256 * i];
    }
    {   // stage 8 rows of x
        const float4* X4 = (const float4*)(x + (size_t)row0 * IN_DIM);
        ((float4*)&Xs[0][0])[tid] = X4[tid];
    }
    __syncthreads();

    const int r = tid >> 5, col = tid & 31;
    const int row = row0 + r;
    float acc = 0.f;
    #pragma unroll
    for (int k = 0; k < IN_DIM; k += 4) {
        float4 xv = *(const float4*)&Xs[r][k];
        acc += xv.x * Ws[k][col] + xv.y * Ws[k + 1][col]
             + xv.z * Ws[k + 2][col] + xv.w * Ws[k + 3][col];
    }
    h[(size_t)row * HID + col] = __float2bfloat16(acc);   // bf16: halves gather traffic

    float elp = acc * al[col];
    float erp = acc * ar[col];
    #pragma unroll
    for (int m = 16; m > 0; m >>= 1) {
        elp += __shfl_xor(elp, m, 32);
        erp += __shfl_xor(erp, m, 32);
    }
    if (col == 0) { el[row] = elp; er[row] = erp; }
}

// ======================= Bucket histogram =============================================
__global__ __launch_bounds__(256) void bhist_kernel(const int* __restrict__ dst,
                                                    int* __restrict__ bucket_cnt)
{
    __shared__ int hist[NBUCK];
    const int tid = threadIdx.x;
    for (int i = tid; i < NBUCK; i += 256) hist[i] = 0;
    __syncthreads();
    const int t = blockIdx.x * 256 + tid;         // 16-edge group id
    if (t < N_EDGES / 16) {
        const int4* d4 = (const int4*)dst + (size_t)t * 4;
        #pragma unroll
        for (int q = 0; q < 4; ++q) {
            const int4 d = d4[q];
            atomicAdd(&hist[d.x >> 7], 1); atomicAdd(&hist[d.y >> 7], 1);
            atomicAdd(&hist[d.z >> 7], 1); atomicAdd(&hist[d.w >> 7], 1);
        }
    }
    __syncthreads();
    for (int i = tid; i < NBUCK; i += 256) {
        const int hv = hist[i];
        if (hv) atomicAdd(&bucket_cnt[i], hv);
    }
}

// ======================= Bucket scan (1 block) ========================================
__global__ __launch_bounds__(1024) void bscan_kernel(const int* __restrict__ cnt,
                                                     int* __restrict__ base,
                                                     int* __restrict__ gcur)
{
    const int t = threadIdx.x;
    const int v = (t < NBUCK) ? cnt[t] : 0;
    const int lane = t & 63, wid = t >> 6;        // 16 waves
    int pre = v;
    #pragma unroll
    for (int off = 1; off < 64; off <<= 1) {
        const int n = __shfl_up(pre, off, 64);
        if (lane >= off) pre += n;
    }
    __shared__ int ws[16];
    if (lane == 63) ws[wid] = pre;
    __syncthreads();
    int wo = 0;
    for (int k = 0; k < wid; ++k) wo += ws[k];
    const int ex = wo + pre - v;                  // exclusive prefix
    if (t < NBUCK) { base[t] = ex; gcur[t] = ex; }
}

// ======================= Binning (block-aggregated multisplit, packed 4B) =============
__global__ __launch_bounds__(256) void bin_kernel(const int* __restrict__ src,
                                                  const int* __restrict__ dst,
                                                  int* __restrict__ gcur,
                                                  int* __restrict__ pairs)
{
    __shared__ int hist[NBUCK];
    __shared__ int cur[NBUCK];
    const int tid = threadIdx.x;
    for (int i = tid; i < NBUCK; i += 256) hist[i] = 0;
    __syncthreads();

    const int t = blockIdx.x * 256 + tid;         // 16-edge group id
    const bool act = t < N_EDGES / 16;
    int4 sv[4], dv[4];
    if (act) {
        const int4* s4 = (const int4*)src + (size_t)t * 4;
        const int4* d4 = (const int4*)dst + (size_t)t * 4;
        #pragma unroll
        for (int q = 0; q < 4; ++q) { sv[q] = s4[q]; dv[q] = d4[q]; }
        #pragma unroll
        for (int q = 0; q < 4; ++q) {
            atomicAdd(&hist[dv[q].x >> 7], 1); atomicAdd(&hist[dv[q].y >> 7], 1);
            atomicAdd(&hist[dv[q].z >> 7], 1); atomicAdd(&hist[dv[q].w >> 7], 1);
        }
    }
    __syncthreads();
    for (int i = tid; i < NBUCK; i += 256) {
        const int hv = hist[i];
        cur[i] = hv ? atomicAdd(&gcur[i], hv) : 0;
    }
    __syncthreads();
    if (act) {
        #pragma unroll
        for (int q = 0; q < 4; ++q) {
            const int ss[4] = {sv[q].x, sv[q].y, sv[q].z, sv[q].w};
            const int dd[4] = {dv[q].x, dv[q].y, dv[q].z, dv[q].w};
            #pragma unroll
            for (int r = 0; r < 4; ++r) {
                const int slot = atomicAdd(&cur[dd[r] >> 7], 1);
                pairs[slot] = (ss[r] << 7) | (dd[r] & (BW - 1));
            }
        }
    }
}

// ======================= Bucket-local sort -> node CSR + layer-1 weights ==============
// One block per bucket; all scatter targets in an ~8 KB L2-resident window.
// Fuses layer-1 weight computation: w1[slot] = exp(leakyrelu(el1[src] + er1[dst])).
__global__ __launch_bounds__(256) void lsort_kernel(
    const int* __restrict__ bucket_base, const int* __restrict__ bucket_cnt,
    const int* __restrict__ pairs,
    const float* __restrict__ el, const float* __restrict__ er,
    int* __restrict__ deg, int* __restrict__ rowptr,
    int* __restrict__ csr, float* __restrict__ w1)
{
    __shared__ int lhist[BW];
    __shared__ int lcur[BW];
    __shared__ float ers[BW];
    __shared__ int w0tot;
    const int tid = threadIdx.x;
    const int b = blockIdx.x;
    const int node0 = b * BW;
    if (tid < BW) {
        lhist[tid] = 0;
        ers[tid] = (node0 + tid < N_NODES) ? er[node0 + tid] : 0.f;
    }
    __syncthreads();
    const int ebase = bucket_base[b];
    const int ecnt  = bucket_cnt[b];
    for (int i = tid; i < ecnt; i += 256)
        atomicAdd(&lhist[pairs[ebase + i] & (BW - 1)], 1);
    __syncthreads();
    // exclusive scan of the 128 local degrees (2 waves)
    const int lane = tid & 63;
    int v = 0;
    if (tid < BW) v = lhist[tid];
    int pre = v;
    #pragma unroll
    for (int off = 1; off < 64; off <<= 1) {
        const int n = __shfl_up(pre, off, 64);
        if (lane >= off) pre += n;
    }
    if (tid == 63) w0tot = pre;
    __syncthreads();
    if (tid < BW) {
        const int ex = pre - v + (tid >= 64 ? w0tot : 0);
        lcur[tid] = ex;
        const int node = node0 + tid;
        if (node < N_NODES) { deg[node] = v; rowptr[node] = ebase + ex; }
    }
    __syncthreads();
    for (int i = tid; i < ecnt; i += 256) {
        const int p = pairs[ebase + i];
        const int ldst = p & (BW - 1);
        const int slot = atomicAdd(&lcur[ldst], 1);
        csr[ebase + slot] = p;
        float sc = el[p >> 7] + ers[ldst];
        sc = sc > 0.f ? sc : 0.2f * sc;              // LeakyReLU(0.2)
        w1[ebase + slot] = __expf(sc);
    }
}

// ======================= Layer-2 weights ==============================================
// Streaming: w2[slot] = exp(leakyrelu(el2[src] + er2[dst])); csr sequential, el2 in L2.
__global__ __launch_bounds__(256) void wcalc_kernel(
    const int* __restrict__ bucket_base, const int* __restrict__ bucket_cnt,
    const int* __restrict__ csr,
    const float* __restrict__ el, const float* __restrict__ er,
    float* __restrict__ w)
{
    __shared__ float ers[BW];
    const int tid = threadIdx.x;
    const int b = blockIdx.x;
    const int node0 = b * BW;
    if (tid < BW) ers[tid] = (node0 + tid < N_NODES) ? er[node0 + tid] : 0.f;
    __syncthreads();
    const int ebase = bucket_base[b];
    const int ecnt  = bucket_cnt[b];
    for (int i = tid; i < ecnt; i += 256) {
        const int p = csr[ebase + i];
        float sc = el[p >> 7] + ers[p & (BW - 1)];
        sc = sc > 0.f ? sc : 0.2f * sc;
        w[ebase + i] = __expf(sc);
    }
}

// ======================= Gather-aggregate (both layers) ===============================
// One node per 32-lane group (8 nodes/block); pure weighted average: w/csr are
// sequential broadcast loads, h is the single dependent random stream (bf16, 64B/row).
// All 32 lanes redundantly accumulate den (broadcast w) -> no cross-lane reduction.
// MODE 0: out = elu(num/den + b)   MODE 1: out = num/den + b
template <int MODE>
__global__ __launch_bounds__(256) void gather_kernel(
    const int* __restrict__ rowptr, const int* __restrict__ deg,
    const int* __restrict__ csr, const float* __restrict__ w,
    const __hip_bfloat16* __restrict__ h, const float* __restrict__ bias,
    float* __restrict__ out)
{
    const int tid = threadIdx.x;
    const int node = blockIdx.x * 8 + (tid >> 5);    // grid = N/8 exactly
    const int col = tid & 31;
    const int cnt = deg[node];
    const int start = rowptr[node];
    float acc = 0.f, den = 0.f;
    int j = 0;
    for (; j + 3 < cnt; j += 4) {
        const int p0 = csr[start + j];
        const int p1 = csr[start + j + 1];
        const int p2 = csr[start + j + 2];
        const int p3 = csr[start + j + 3];
        const float w0 = w[start + j];
        const float w1v = w[start + j + 1];
        const float w2v = w[start + j + 2];
        const float w3v = w[start + j + 3];
        const float h0 = __bfloat162float(h[(size_t)(p0 >> 7) * HID + col]);
        const float h1 = __bfloat162float(h[(size_t)(p1 >> 7) * HID + col]);
        const float h2 = __bfloat162float(h[(size_t)(p2 >> 7) * HID + col]);
        const float h3 = __bfloat162float(h[(size_t)(p3 >> 7) * HID + col]);
        den += (w0 + w1v) + (w2v + w3v);
        acc += w0 * h0 + w1v * h1 + w2v * h2 + w3v * h3;
    }
    for (; j < cnt; ++j) {
        const int p = csr[start + j];
        const float wv = w[start + j];
        den += wv;
        acc += wv * __bfloat162float(h[(size_t)(p >> 7) * HID + col]);
    }
    float v = den > 0.f ? acc / den : 0.f;
    v += bias[col];
    if (MODE == 0) v = v > 0.f ? v : expm1f(v);      // ELU
    out[(size_t)node * HID + col] = v;
}

// ======================= Layer-2 GEMM: h2(bf16) = x2@W2, el2, er2 =====================
__global__ __launch_bounds__(256) void gemm2_kernel(
    const float* __restrict__ x2, const float* __restrict__ W,
    const float* __restrict__ al, const float* __restrict__ ar,
    __hip_bfloat16* __restrict__ h, float* __restrict__ el, float* __restrict__ er)
{
    __shared__ float Ws[HID][HID];  // 4 KB
    __shared__ float Xs[8][HID];    // 1 KB
    const int tid = threadIdx.x;
    const int row0 = blockIdx.x * 8;
    const int r = tid >> 5, c = tid & 31;
    const int row = row0 + r;

    ((float4*)&Ws[0][0])[tid] = ((const float4*)W)[tid];
    Xs[r][c] = x2[(size_t)row * HID + c];
    __syncthreads();

    float acc = 0.f;
    #pragma unroll
    for (int k = 0; k < HID; ++k) acc += Xs[r][k] * Ws[k][c];
    h[(size_t)row * HID + c] = __float2bfloat16(acc);

    float elp = acc * al[c];
    float erp = acc * ar[c];
    #pragma unroll
    for (int m = 16; m > 0; m >>= 1) {
        elp += __shfl_xor(elp, m, 32);
        erp += __shfl_xor(erp, m, 32);
    }
    if (c == 0) { el[row] = elp; er[row] = erp; }
}

extern "C" void kernel_launch(void* const* d_in, const int* in_sizes, int n_in,
                              void* d_out, int out_size, void* d_ws, size_t ws_size,
                              hipStream_t stream) {
    const float* features = (const float*)d_in[0];
    const int*   src      = (const int*)d_in[1];
    const int*   dst      = (const int*)d_in[2];
    const float* W1       = (const float*)d_in[3];
    const float* al1      = (const float*)d_in[4];
    const float* ar1      = (const float*)d_in[5];
    const float* b1       = (const float*)d_in[6];
    const float* W2       = (const float*)d_in[7];
    const float* al2      = (const float*)d_in[8];
    const float* ar2      = (const float*)d_in[9];
    const float* b2       = (const float*)d_in[10];
    float* out = (float*)d_out;

    // Workspace (~41 MB).  h2 aliases h1, el2/er2 alias el1/er1, w shared by layers.
    int*  bucket_cnt  = (int*)d_ws;                    // 784
    int*  bucket_base = bucket_cnt + 784;              // 784
    int*  gcur        = bucket_base + 784;             // 784
    int*  deg         = gcur + 784;                    // 100k
    int*  rowptr      = deg + N_NODES;                 // 100k
    int*  csr         = rowptr + N_NODES;              // 1.6M packed (6.4 MB)
    int*  pairs       = csr + N_EDGES;                 // 1.6M packed (6.4 MB)
    float* wbuf       = (float*)(pairs + N_EDGES);     // 1.6M (6.4 MB)
    __hip_bfloat16* h = (__hip_bfloat16*)(wbuf + N_EDGES);  // 3.2M bf16 (6.4 MB)
    float* el  = (float*)(h + (size_t)N_NODES * HID);
    float* er  = el + N_NODES;
    float* x2  = er + N_NODES;                         // 12.8 MB

    const int NB_E16 = (N_EDGES / 16 + 255) / 256;     // 391

    // Layer-1 GEMM (+ zero bucket_cnt)
    gemm1_kernel<<<N_NODES / 8, 256, 0, stream>>>(features, W1, al1, ar1,
                                                  h, el, er, bucket_cnt);
    // CSR build: bucket hist -> scan -> bin (packed) -> local sort (+ layer-1 weights)
    bhist_kernel<<<NB_E16, 256, 0, stream>>>(dst, bucket_cnt);
    bscan_kernel<<<1, 1024, 0, stream>>>(bucket_cnt, bucket_base, gcur);
    bin_kernel<<<NB_E16, 256, 0, stream>>>(src, dst, gcur, pairs);
    lsort_kernel<<<NBUCK, 256, 0, stream>>>(bucket_base, bucket_cnt, pairs,
                                            el, er, deg, rowptr, csr, wbuf);
    // Layer-1 aggregate -> x2 = elu(num/den + b1)
    gather_kernel<0><<<N_NODES / 8, 256, 0, stream>>>(rowptr, deg, csr, wbuf,
                                                      h, b1, x2);
    // Layer-2 GEMM (h2/el2/er2 overwrite layer-1 buffers)
    gemm2_kernel<<<N_NODES / 8, 256, 0, stream>>>(x2, W2, al2, ar2, h, el, er);
    // Layer-2 weights + aggregate -> out = num/den + b2
    wcalc_kernel<<<NBUCK, 256, 0, stream>>>(bucket_base, bucket_cnt, csr,
                                            el, er, wbuf);
    gather_kernel<1><<<N_NODES / 8, 256, 0, stream>>>(rowptr, deg, csr, wbuf,
                                                      h, b2, out);
}

// Round 7
// 278.934 us; speedup vs baseline: 3.2136x; 1.1208x over previous
//
#include <hip/hip_runtime.h>
#include <hip/hip_bf16.h>

#define N_NODES 100000
#define N_EDGES 1600000
#define IN_DIM 128
#define HID 32
#define BW 128                                   // bucket width (dst nodes)
#define NBUCK ((N_NODES + BW - 1) / BW)          // 782

// Packed edge: (src << 7) | local_dst.  src < 2^17, local_dst < 128.

using bf16x8 = __attribute__((ext_vector_type(8))) short;
using f32x4  = __attribute__((ext_vector_type(4))) float;

__device__ __forceinline__ short f2bf(float f) {
    return __builtin_bit_cast(short, __float2bfloat16(f));
}
__device__ __forceinline__ float bf2f(short s) {
    return __bfloat162float(__builtin_bit_cast(__hip_bfloat16, s));
}

// ======================= Layer-1 GEMM (MFMA, hi/lo bf16 = f32 accuracy) ===============
// h1(bf16) = x@W1; el1/er1 from f32 accumulators. Zeroes bucket_cnt.
// Wave = 16 rows x 32 cols; K=128 in 4 chunks; 3 MFMAs/chunk/col-tile (hh, lh, hl).
__global__ __launch_bounds__(256) void gemm1_kernel(
    const float* __restrict__ x, const float* __restrict__ W,
    const float* __restrict__ al, const float* __restrict__ ar,
    __hip_bfloat16* __restrict__ h, float* __restrict__ el, float* __restrict__ er,
    int* __restrict__ bucket_cnt)
{
    __shared__ float Xs[64][132];    // 64 rows x 128 (+4 pad) = 33 KB
    const int tid = threadIdx.x;
    const int row0 = blockIdx.x * 64;

    const int gid = blockIdx.x * 256 + tid;
    if (gid < NBUCK) bucket_cnt[gid] = 0;

    const int lane = tid & 63, wid = tid >> 6;
    const int l15 = lane & 15, g = lane >> 4;

    // B fragments: W hi/lo, 4 k-chunks x 2 col-tiles. Slot (g,j) <- k = 32q+8g+j.
    bf16x8 bh[4][2], bl[4][2];
    #pragma unroll
    for (int q = 0; q < 4; ++q)
        #pragma unroll
        for (int ct = 0; ct < 2; ++ct)
            #pragma unroll
            for (int j = 0; j < 8; ++j) {
                const float wv = W[(32 * q + 8 * g + j) * HID + ct * 16 + l15];
                const short hi = f2bf(wv);
                bh[q][ct][j] = hi;
                bl[q][ct][j] = f2bf(wv - bf2f(hi));
            }

    // Stage 64 rows of x (coalesced float4)
    #pragma unroll
    for (int i = 0; i < 8; ++i) {
        const int f = tid + 256 * i;
        const int r = f >> 5, c4 = f & 31;
        const int gr = row0 + r;
        float4 v = make_float4(0.f, 0.f, 0.f, 0.f);
        if (gr < N_NODES) v = ((const float4*)x)[(size_t)gr * 32 + c4];
        *(float4*)&Xs[r][c4 * 4] = v;
    }
    __syncthreads();

    const int tile = blockIdx.x * 4 + wid;       // 16-row tile id
    if (tile * 16 >= N_NODES) return;            // N%16==0: no partial tiles
    const int rl = wid * 16 + l15;               // local row for A fragment

    f32x4 acc0 = {0.f, 0.f, 0.f, 0.f}, acc1 = {0.f, 0.f, 0.f, 0.f};
    #pragma unroll
    for (int q = 0; q < 4; ++q) {
        const float4 xa = *(const float4*)&Xs[rl][32 * q + 8 * g];
        const float4 xb = *(const float4*)&Xs[rl][32 * q + 8 * g + 4];
        const float xs[8] = {xa.x, xa.y, xa.z, xa.w, xb.x, xb.y, xb.z, xb.w};
        bf16x8 ah, alo;
        #pragma unroll
        for (int j = 0; j < 8; ++j) {
            const short hi = f2bf(xs[j]);
            ah[j] = hi;
            alo[j] = f2bf(xs[j] - bf2f(hi));
        }
        acc0 = __builtin_amdgcn_mfma_f32_16x16x32_bf16(ah,  bh[q][0], acc0, 0, 0, 0);
        acc0 = __builtin_amdgcn_mfma_f32_16x16x32_bf16(alo, bh[q][0], acc0, 0, 0, 0);
        acc0 = __builtin_amdgcn_mfma_f32_16x16x32_bf16(ah,  bl[q][0], acc0, 0, 0, 0);
        acc1 = __builtin_amdgcn_mfma_f32_16x16x32_bf16(ah,  bh[q][1], acc1, 0, 0, 0);
        acc1 = __builtin_amdgcn_mfma_f32_16x16x32_bf16(alo, bh[q][1], acc1, 0, 0, 0);
        acc1 = __builtin_amdgcn_mfma_f32_16x16x32_bf16(ah,  bl[q][1], acc1, 0, 0, 0);
    }

    // Epilogue. D layout (verified): col = lane&15, row = (lane>>4)*4 + reg.
    const int grow0 = tile * 16 + 4 * g;
    const float a0 = al[l15], a1 = al[16 + l15];
    const float r0 = ar[l15], r1 = ar[16 + l15];
    float pel[4], per_[4];
    #pragma unroll
    for (int i = 0; i < 4; ++i) {
        const int grow = grow0 + i;
        h[(size_t)grow * HID + l15]      = __float2bfloat16(acc0[i]);
        h[(size_t)grow * HID + 16 + l15] = __float2bfloat16(acc1[i]);
        pel[i]  = acc0[i] * a0 + acc1[i] * a1;
        per_[i] = acc0[i] * r0 + acc1[i] * r1;
    }
    #pragma unroll
    for (int m = 1; m < 16; m <<= 1)
        #pragma unroll
        for (int i = 0; i < 4; ++i) {
            pel[i]  += __shfl_xor(pel[i],  m, 16);
            per_[i] += __shfl_xor(per_[i], m, 16);
        }
    if (l15 == 0)
        #pragma unroll
        for (int i = 0; i < 4; ++i) { el[grow0 + i] = pel[i]; er[grow0 + i] = per_[i]; }
}

// ======================= Bucket histogram =============================================
__global__ __launch_bounds__(256) void bhist_kernel(const int* __restrict__ dst,
                                                    int* __restrict__ bucket_cnt)
{
    __shared__ int hist[NBUCK];
    const int tid = threadIdx.x;
    for (int i = tid; i < NBUCK; i += 256) hist[i] = 0;
    __syncthreads();
    const int t = blockIdx.x * 256 + tid;         // 16-edge group id
    if (t < N_EDGES / 16) {
        const int4* d4 = (const int4*)dst + (size_t)t * 4;
        #pragma unroll
        for (int q = 0; q < 4; ++q) {
            const int4 d = d4[q];
            atomicAdd(&hist[d.x >> 7], 1); atomicAdd(&hist[d.y >> 7], 1);
            atomicAdd(&hist[d.z >> 7], 1); atomicAdd(&hist[d.w >> 7], 1);
        }
    }
    __syncthreads();
    for (int i = tid; i < NBUCK; i += 256) {
        const int hv = hist[i];
        if (hv) atomicAdd(&bucket_cnt[i], hv);
    }
}

// ======================= Bucket scan (1 block) ========================================
__global__ __launch_bounds__(1024) void bscan_kernel(const int* __restrict__ cnt,
                                                     int* __restrict__ base,
                                                     int* __restrict__ gcur)
{
    const int t = threadIdx.x;
    const int v = (t < NBUCK) ? cnt[t] : 0;
    const int lane = t & 63, wid = t >> 6;        // 16 waves
    int pre = v;
    #pragma unroll
    for (int off = 1; off < 64; off <<= 1) {
        const int n = __shfl_up(pre, off, 64);
        if (lane >= off) pre += n;
    }
    __shared__ int ws[16];
    if (lane == 63) ws[wid] = pre;
    __syncthreads();
    int wo = 0;
    for (int k = 0; k < wid; ++k) wo += ws[k];
    const int ex = wo + pre - v;                  // exclusive prefix
    if (t < NBUCK) { base[t] = ex; gcur[t] = ex; }
}

// ======================= Binning (block-aggregated multisplit, packed 4B) =============
__global__ __launch_bounds__(256) void bin_kernel(const int* __restrict__ src,
                                                  const int* __restrict__ dst,
                                                  int* __restrict__ gcur,
                                                  int* __restrict__ pairs)
{
    __shared__ int hist[NBUCK];
    __shared__ int cur[NBUCK];
    const int tid = threadIdx.x;
    for (int i = tid; i < NBUCK; i += 256) hist[i] = 0;
    __syncthreads();

    const int t = blockIdx.x * 256 + tid;         // 16-edge group id
    const bool act = t < N_EDGES / 16;
    int4 sv[4], dv[4];
    if (act) {
        const int4* s4 = (const int4*)src + (size_t)t * 4;
        const int4* d4 = (const int4*)dst + (size_t)t * 4;
        #pragma unroll
        for (int q = 0; q < 4; ++q) { sv[q] = s4[q]; dv[q] = d4[q]; }
        #pragma unroll
        for (int q = 0; q < 4; ++q) {
            atomicAdd(&hist[dv[q].x >> 7], 1); atomicAdd(&hist[dv[q].y >> 7], 1);
            atomicAdd(&hist[dv[q].z >> 7], 1); atomicAdd(&hist[dv[q].w >> 7], 1);
        }
    }
    __syncthreads();
    for (int i = tid; i < NBUCK; i += 256) {
        const int hv = hist[i];
        cur[i] = hv ? atomicAdd(&gcur[i], hv) : 0;
    }
    __syncthreads();
    if (act) {
        #pragma unroll
        for (int q = 0; q < 4; ++q) {
            const int ss[4] = {sv[q].x, sv[q].y, sv[q].z, sv[q].w};
            const int dd[4] = {dv[q].x, dv[q].y, dv[q].z, dv[q].w};
            #pragma unroll
            for (int r = 0; r < 4; ++r) {
                const int slot = atomicAdd(&cur[dd[r] >> 7], 1);
                pairs[slot] = (ss[r] << 7) | (dd[r] & (BW - 1));
            }
        }
    }
}

// ======================= Bucket-local sort -> node CSR + layer-1 weights ==============
__global__ __launch_bounds__(256) void lsort_kernel(
    const int* __restrict__ bucket_base, const int* __restrict__ bucket_cnt,
    const int* __restrict__ pairs,
    const float* __restrict__ el, const float* __restrict__ er,
    int* __restrict__ deg, int* __restrict__ rowptr,
    int* __restrict__ csr, float* __restrict__ w1)
{
    __shared__ int lhist[BW];
    __shared__ int lcur[BW];
    __shared__ float ers[BW];
    __shared__ int w0tot;
    const int tid = threadIdx.x;
    const int b = blockIdx.x;
    const int node0 = b * BW;
    if (tid < BW) {
        lhist[tid] = 0;
        ers[tid] = (node0 + tid < N_NODES) ? er[node0 + tid] : 0.f;
    }
    __syncthreads();
    const int ebase = bucket_base[b];
    const int ecnt  = bucket_cnt[b];
    for (int i = tid; i < ecnt; i += 256)
        atomicAdd(&lhist[pairs[ebase + i] & (BW - 1)], 1);
    __syncthreads();
    const int lane = tid & 63;
    int v = 0;
    if (tid < BW) v = lhist[tid];
    int pre = v;
    #pragma unroll
    for (int off = 1; off < 64; off <<= 1) {
        const int n = __shfl_up(pre, off, 64);
        if (lane >= off) pre += n;
    }
    if (tid == 63) w0tot = pre;
    __syncthreads();
    if (tid < BW) {
        const int ex = pre - v + (tid >= 64 ? w0tot : 0);
        lcur[tid] = ex;
        const int node = node0 + tid;
        if (node < N_NODES) { deg[node] = v; rowptr[node] = ebase + ex; }
    }
    __syncthreads();
    for (int i = tid; i < ecnt; i += 256) {
        const int p = pairs[ebase + i];
        const int ldst = p & (BW - 1);
        const int slot = atomicAdd(&lcur[ldst], 1);
        csr[ebase + slot] = p;
        float sc = el[p >> 7] + ers[ldst];
        sc = sc > 0.f ? sc : 0.2f * sc;              // LeakyReLU(0.2)
        w1[ebase + slot] = __expf(sc);
    }
}

// ======================= Layer-2 weights ==============================================
__global__ __launch_bounds__(256) void wcalc_kernel(
    const int* __restrict__ bucket_base, const int* __restrict__ bucket_cnt,
    const int* __restrict__ csr,
    const float* __restrict__ el, const float* __restrict__ er,
    float* __restrict__ w)
{
    __shared__ float ers[BW];
    const int tid = threadIdx.x;
    const int b = blockIdx.x;
    const int node0 = b * BW;
    if (tid < BW) ers[tid] = (node0 + tid < N_NODES) ? er[node0 + tid] : 0.f;
    __syncthreads();
    const int ebase = bucket_base[b];
    const int ecnt  = bucket_cnt[b];
    for (int i = tid; i < ecnt; i += 256) {
        const int p = csr[ebase + i];
        float sc = el[p >> 7] + ers[p & (BW - 1)];
        sc = sc > 0.f ? sc : 0.2f * sc;
        w[ebase + i] = __expf(sc);
    }
}

// ======================= Gather-aggregate (both layers) ===============================
// MODE 0: out = elu(num/den + b)   MODE 1: out = num/den + b
template <int MODE>
__global__ __launch_bounds__(256) void gather_kernel(
    const int* __restrict__ rowptr, const int* __restrict__ deg,
    const int* __restrict__ csr, const float* __restrict__ w,
    const __hip_bfloat16* __restrict__ h, const float* __restrict__ bias,
    float* __restrict__ out)
{
    const int tid = threadIdx.x;
    const int node = blockIdx.x * 8 + (tid >> 5);    // grid = N/8 exactly
    const int col = tid & 31;
    const int cnt = deg[node];
    const int start = rowptr[node];
    float acc = 0.f, den = 0.f;
    int j = 0;
    for (; j + 3 < cnt; j += 4) {
        const int p0 = csr[start + j];
        const int p1 = csr[start + j + 1];
        const int p2 = csr[start + j + 2];
        const int p3 = csr[start + j + 3];
        const float w0 = w[start + j];
        const float w1v = w[start + j + 1];
        const float w2v = w[start + j + 2];
        const float w3v = w[start + j + 3];
        const float h0 = __bfloat162float(h[(size_t)(p0 >> 7) * HID + col]);
        const float h1 = __bfloat162float(h[(size_t)(p1 >> 7) * HID + col]);
        const float h2 = __bfloat162float(h[(size_t)(p2 >> 7) * HID + col]);
        const float h3 = __bfloat162float(h[(size_t)(p3 >> 7) * HID + col]);
        den += (w0 + w1v) + (w2v + w3v);
        acc += w0 * h0 + w1v * h1 + w2v * h2 + w3v * h3;
    }
    for (; j < cnt; ++j) {
        const int p = csr[start + j];
        const float wv = w[start + j];
        den += wv;
        acc += wv * __bfloat162float(h[(size_t)(p >> 7) * HID + col]);
    }
    float v = den > 0.f ? acc / den : 0.f;
    v += bias[col];
    if (MODE == 0) v = v > 0.f ? v : expm1f(v);      // ELU
    out[(size_t)node * HID + col] = v;
}

// ======================= Layer-2 GEMM (register-blocked 1x4) ==========================
// h2(bf16) = x2@W2; thread = (row, 4 cols): 2 LDS reads per 4 FMAs.
__global__ __launch_bounds__(256) void gemm2_kernel(
    const float* __restrict__ x2, const float* __restrict__ W,
    const float* __restrict__ al, const float* __restrict__ ar,
    __hip_bfloat16* __restrict__ h, float* __restrict__ el, float* __restrict__ er)
{
    __shared__ float Ws[HID][36];   // pad 36: float4-aligned rows, conflict-free
    __shared__ float Xs[32][36];
    const int tid = threadIdx.x;
    const int row0 = blockIdx.x * 32;
    {
        const float4 wv = ((const float4*)W)[tid];
        *(float4*)&Ws[tid >> 3][(tid & 7) * 4] = wv;
        const float4 xv = ((const float4*)x2)[(size_t)row0 * 8 + tid];
        *(float4*)&Xs[tid >> 3][(tid & 7) * 4] = xv;
    }
    __syncthreads();

    const int r = tid >> 3, cg = tid & 7;
    const int row = row0 + r;
    float ax = 0.f, ay = 0.f, az = 0.f, aw = 0.f;
    #pragma unroll
    for (int k = 0; k < HID; ++k) {
        const float xv = Xs[r][k];
        const float4 wv = *(const float4*)&Ws[k][cg * 4];
        ax += xv * wv.x; ay += xv * wv.y; az += xv * wv.z; aw += xv * wv.w;
    }

    ushort4 hp;
    hp.x = __builtin_bit_cast(unsigned short, __float2bfloat16(ax));
    hp.y = __builtin_bit_cast(unsigned short, __float2bfloat16(ay));
    hp.z = __builtin_bit_cast(unsigned short, __float2bfloat16(az));
    hp.w = __builtin_bit_cast(unsigned short, __float2bfloat16(aw));
    *(ushort4*)&h[(size_t)row * HID + cg * 4] = hp;

    const int c0 = cg * 4;
    float pel = ax * al[c0] + ay * al[c0 + 1] + az * al[c0 + 2] + aw * al[c0 + 3];
    float per = ax * ar[c0] + ay * ar[c0 + 1] + az * ar[c0 + 2] + aw * ar[c0 + 3];
    #pragma unroll
    for (int m = 1; m < 8; m <<= 1) {
        pel += __shfl_xor(pel, m, 8);
        per += __shfl_xor(per, m, 8);
    }
    if (cg == 0) { el[row] = pel; er[row] = per; }
}

extern "C" void kernel_launch(void* const* d_in, const int* in_sizes, int n_in,
                              void* d_out, int out_size, void* d_ws, size_t ws_size,
                              hipStream_t stream) {
    const float* features = (const float*)d_in[0];
    const int*   src      = (const int*)d_in[1];
    const int*   dst      = (const int*)d_in[2];
    const float* W1       = (const float*)d_in[3];
    const float* al1      = (const float*)d_in[4];
    const float* ar1      = (const float*)d_in[5];
    const float* b1       = (const float*)d_in[6];
    const float* W2       = (const float*)d_in[7];
    const float* al2      = (const float*)d_in[8];
    const float* ar2      = (const float*)d_in[9];
    const float* b2       = (const float*)d_in[10];
    float* out = (float*)d_out;

    // Workspace (~41 MB).  h2 aliases h1, el2/er2 alias el1/er1, w shared by layers.
    int*  bucket_cnt  = (int*)d_ws;                    // 784
    int*  bucket_base = bucket_cnt + 784;              // 784
    int*  gcur        = bucket_base + 784;             // 784
    int*  deg         = gcur + 784;                    // 100k
    int*  rowptr      = deg + N_NODES;                 // 100k
    int*  csr         = rowptr + N_NODES;              // 1.6M packed (6.4 MB)
    int*  pairs       = csr + N_EDGES;                 // 1.6M packed (6.4 MB)
    float* wbuf       = (float*)(pairs + N_EDGES);     // 1.6M (6.4 MB)
    __hip_bfloat16* h = (__hip_bfloat16*)(wbuf + N_EDGES);  // 3.2M bf16 (6.4 MB)
    float* el  = (float*)(h + (size_t)N_NODES * HID);
    float* er  = el + N_NODES;
    float* x2  = er + N_NODES;                         // 12.8 MB

    const int NB_E16 = (N_EDGES / 16 + 255) / 256;     // 391
    const int NB_G1  = (N_NODES + 63) / 64;            // 1563 (64 rows/block)

    // Layer-1 GEMM (MFMA, + zero bucket_cnt)
    gemm1_kernel<<<NB_G1, 256, 0, stream>>>(features, W1, al1, ar1,
                                            h, el, er, bucket_cnt);
    // CSR build: bucket hist -> scan -> bin (packed) -> local sort (+ layer-1 weights)
    bhist_kernel<<<NB_E16, 256, 0, stream>>>(dst, bucket_cnt);
    bscan_kernel<<<1, 1024, 0, stream>>>(bucket_cnt, bucket_base, gcur);
    bin_kernel<<<NB_E16, 256, 0, stream>>>(src, dst, gcur, pairs);
    lsort_kernel<<<NBUCK, 256, 0, stream>>>(bucket_base, bucket_cnt, pairs,
                                            el, er, deg, rowptr, csr, wbuf);
    // Layer-1 aggregate -> x2 = elu(num/den + b1)
    gather_kernel<0><<<N_NODES / 8, 256, 0, stream>>>(rowptr, deg, csr, wbuf,
                                                      h, b1, x2);
    // Layer-2 GEMM (h2/el2/er2 overwrite layer-1 buffers)
    gemm2_kernel<<<N_NODES / 32, 256, 0, stream>>>(x2, W2, al2, ar2, h, el, er);
    // Layer-2 weights + aggregate -> out = num/den + b2
    wcalc_kernel<<<NBUCK, 256, 0, stream>>>(bucket_base, bucket_cnt, csr,
                                            el, er, wbuf);
    gather_kernel<1><<<N_NODES / 8, 256, 0, stream>>>(rowptr, deg, csr, wbuf,
                                                      h, b2, out);
}

// Round 9
// 237.863 us; speedup vs baseline: 3.7685x; 1.1727x over previous
//
#include <hip/hip_runtime.h>
#include <hip/hip_bf16.h>

#define N_NODES 100000
#define N_EDGES 1600000
#define IN_DIM 128
#define HID 32
#define BW 128                                   // bucket width (dst nodes)
#define NBUCK ((N_NODES + BW - 1) / BW)          // 782
#define CAP 4096                                 // fixed region per bucket (max cnt ~2300)

// Packed edge: (src << 7) | local_dst.  src < 2^17, local_dst < 128.

using bf16x8 = __attribute__((ext_vector_type(8))) short;
using f32x4  = __attribute__((ext_vector_type(4))) float;

__device__ __forceinline__ short f2bf(float f) {
    return __builtin_bit_cast(short, __float2bfloat16(f));
}
__device__ __forceinline__ float bf2f(short s) {
    return __bfloat162float(__builtin_bit_cast(__hip_bfloat16, s));
}

// ======================= Layer-1 GEMM (MFMA, hi/lo bf16 = f32 accuracy) ===============
// h1(bf16) = x@W1; el1/er1 from f32 accumulators. Inits gcur[b] = b*CAP.
__global__ __launch_bounds__(256) void gemm1_kernel(
    const float* __restrict__ x, const float* __restrict__ W,
    const float* __restrict__ al, const float* __restrict__ ar,
    __hip_bfloat16* __restrict__ h, float* __restrict__ el, float* __restrict__ er,
    int* __restrict__ gcur)
{
    __shared__ float Xs[64][132];    // 64 rows x 128 (+4 pad) = 33 KB
    const int tid = threadIdx.x;
    const int row0 = blockIdx.x * 64;

    const int gid = blockIdx.x * 256 + tid;
    if (gid < NBUCK) gcur[gid] = gid * CAP;      // cursor init (no bhist/bscan needed)

    const int lane = tid & 63, wid = tid >> 6;
    const int l15 = lane & 15, g = lane >> 4;

    // B fragments: W hi/lo, 4 k-chunks x 2 col-tiles. Slot (g,j) <- k = 32q+8g+j.
    bf16x8 bh[4][2], bl[4][2];
    #pragma unroll
    for (int q = 0; q < 4; ++q)
        #pragma unroll
        for (int ct = 0; ct < 2; ++ct)
            #pragma unroll
            for (int j = 0; j < 8; ++j) {
                const float wv = W[(32 * q + 8 * g + j) * HID + ct * 16 + l15];
                const short hi = f2bf(wv);
                bh[q][ct][j] = hi;
                bl[q][ct][j] = f2bf(wv - bf2f(hi));
            }

    // Stage 64 rows of x (coalesced float4)
    #pragma unroll
    for (int i = 0; i < 8; ++i) {
        const int f = tid + 256 * i;
        const int r = f >> 5, c4 = f & 31;
        const int gr = row0 + r;
        float4 v = make_float4(0.f, 0.f, 0.f, 0.f);
        if (gr < N_NODES) v = ((const float4*)x)[(size_t)gr * 32 + c4];
        *(float4*)&Xs[r][c4 * 4] = v;
    }
    __syncthreads();

    const int tile = blockIdx.x * 4 + wid;       // 16-row tile id
    if (tile * 16 >= N_NODES) return;
    const int rl = wid * 16 + l15;               // local row for A fragment

    f32x4 acc0 = {0.f, 0.f, 0.f, 0.f}, acc1 = {0.f, 0.f, 0.f, 0.f};
    #pragma unroll
    for (int q = 0; q < 4; ++q) {
        const float4 xa = *(const float4*)&Xs[rl][32 * q + 8 * g];
        const float4 xb = *(const float4*)&Xs[rl][32 * q + 8 * g + 4];
        const float xs[8] = {xa.x, xa.y, xa.z, xa.w, xb.x, xb.y, xb.z, xb.w};
        bf16x8 ah, alo;
        #pragma unroll
        for (int j = 0; j < 8; ++j) {
            const short hi = f2bf(xs[j]);
            ah[j] = hi;
            alo[j] = f2bf(xs[j] - bf2f(hi));
        }
        acc0 = __builtin_amdgcn_mfma_f32_16x16x32_bf16(ah,  bh[q][0], acc0, 0, 0, 0);
        acc0 = __builtin_amdgcn_mfma_f32_16x16x32_bf16(alo, bh[q][0], acc0, 0, 0, 0);
        acc0 = __builtin_amdgcn_mfma_f32_16x16x32_bf16(ah,  bl[q][0], acc0, 0, 0, 0);
        acc1 = __builtin_amdgcn_mfma_f32_16x16x32_bf16(ah,  bh[q][1], acc1, 0, 0, 0);
        acc1 = __builtin_amdgcn_mfma_f32_16x16x32_bf16(alo, bh[q][1], acc1, 0, 0, 0);
        acc1 = __builtin_amdgcn_mfma_f32_16x16x32_bf16(ah,  bl[q][1], acc1, 0, 0, 0);
    }

    // Epilogue. D layout (verified): col = lane&15, row = (lane>>4)*4 + reg.
    const int grow0 = tile * 16 + 4 * g;
    const float a0 = al[l15], a1 = al[16 + l15];
    const float r0 = ar[l15], r1 = ar[16 + l15];
    float pel[4], per_[4];
    #pragma unroll
    for (int i = 0; i < 4; ++i) {
        const int grow = grow0 + i;
        h[(size_t)grow * HID + l15]      = __float2bfloat16(acc0[i]);
        h[(size_t)grow * HID + 16 + l15] = __float2bfloat16(acc1[i]);
        pel[i]  = acc0[i] * a0 + acc1[i] * a1;
        per_[i] = acc0[i] * r0 + acc1[i] * r1;
    }
    #pragma unroll
    for (int m = 1; m < 16; m <<= 1)
        #pragma unroll
        for (int i = 0; i < 4; ++i) {
            pel[i]  += __shfl_xor(pel[i],  m, 16);
            per_[i] += __shfl_xor(per_[i], m, 16);
        }
    if (l15 == 0)
        #pragma unroll
        for (int i = 0; i < 4; ++i) { el[grow0 + i] = pel[i]; er[grow0 + i] = per_[i]; }
}

// ======================= Binning (block-aggregated multisplit, fixed regions) =========
// Block LDS-hists its 4096 edges, one global atomic per (block,bucket) reserves a run
// inside the bucket's fixed [b*CAP, (b+1)*CAP) region, LDS-cursor append.
__global__ __launch_bounds__(256) void bin_kernel(const int* __restrict__ src,
                                                  const int* __restrict__ dst,
                                                  int* __restrict__ gcur,
                                                  int* __restrict__ pairs)
{
    __shared__ int hist[NBUCK];
    __shared__ int cur[NBUCK];
    const int tid = threadIdx.x;
    for (int i = tid; i < NBUCK; i += 256) hist[i] = 0;
    __syncthreads();

    const int t = blockIdx.x * 256 + tid;         // 16-edge group id
    const bool act = t < N_EDGES / 16;
    int4 sv[4], dv[4];
    if (act) {
        const int4* s4 = (const int4*)src + (size_t)t * 4;
        const int4* d4 = (const int4*)dst + (size_t)t * 4;
        #pragma unroll
        for (int q = 0; q < 4; ++q) { sv[q] = s4[q]; dv[q] = d4[q]; }
        #pragma unroll
        for (int q = 0; q < 4; ++q) {
            atomicAdd(&hist[dv[q].x >> 7], 1); atomicAdd(&hist[dv[q].y >> 7], 1);
            atomicAdd(&hist[dv[q].z >> 7], 1); atomicAdd(&hist[dv[q].w >> 7], 1);
        }
    }
    __syncthreads();
    for (int i = tid; i < NBUCK; i += 256) {
        const int hv = hist[i];
        cur[i] = hv ? atomicAdd(&gcur[i], hv) : 0;
    }
    __syncthreads();
    if (act) {
        #pragma unroll
        for (int q = 0; q < 4; ++q) {
            const int ss[4] = {sv[q].x, sv[q].y, sv[q].z, sv[q].w};
            const int dd[4] = {dv[q].x, dv[q].y, dv[q].z, dv[q].w};
            #pragma unroll
            for (int r = 0; r < 4; ++r) {
                const int slot = atomicAdd(&cur[dd[r] >> 7], 1);
                pairs[slot] = (ss[r] << 7) | (dd[r] & (BW - 1));
            }
        }
    }
}

// ======================= Bucket-local sort (in LDS, in-place) =========================
// One block per bucket: read region sequentially, hist+scan+scatter in LDS, write the
// sorted order back to the SAME region (both directions fully coalesced).
__global__ __launch_bounds__(256) void lsort_kernel(
    const int* __restrict__ gcur, int* __restrict__ pairs,
    int* __restrict__ deg, int* __restrict__ rowptr)
{
    __shared__ int lp[CAP];     // 16 KB
    __shared__ int lc[CAP];     // 16 KB
    __shared__ int lhist[BW];
    __shared__ int lcur[BW];
    __shared__ int w0tot;
    const int tid = threadIdx.x;
    const int b = blockIdx.x;
    const int rbase = b * CAP;
    int ecnt = gcur[b] - rbase;
    if (ecnt > CAP) ecnt = CAP;                  // safety clamp (never expected)
    if (tid < BW) lhist[tid] = 0;
    __syncthreads();
    for (int i = tid; i < ecnt; i += 256) {
        const int p = pairs[rbase + i];
        lp[i] = p;
        atomicAdd(&lhist[p & (BW - 1)], 1);
    }
    __syncthreads();
    // exclusive scan of 128 local degrees (2 waves)
    const int lane = tid & 63;
    int v = 0;
    if (tid < BW) v = lhist[tid];
    int pre = v;
    #pragma unroll
    for (int off = 1; off < 64; off <<= 1) {
        const int n = __shfl_up(pre, off, 64);
        if (lane >= off) pre += n;
    }
    if (tid == 63) w0tot = pre;
    __syncthreads();
    if (tid < BW) {
        const int ex = pre - v + (tid >= 64 ? w0tot : 0);
        lcur[tid] = ex;
        const int node = b * BW + tid;
        if (node < N_NODES) { deg[node] = v; rowptr[node] = rbase + ex; }
    }
    __syncthreads();
    for (int i = tid; i < ecnt; i += 256) {
        const int p = lp[i];
        const int slot = atomicAdd(&lcur[p & (BW - 1)], 1);
        lc[slot] = p;
    }
    __syncthreads();
    for (int i = tid; i < ecnt; i += 256) pairs[rbase + i] = lc[i];
}

// ======================= Gather-aggregate (fused weights; fused next-layer GEMM) ======
// One node per 32-lane group. Batch-32: each lane computes the softmax weight for one
// of the next 32 edges (coalesced csr read, L2-resident el read, exp), then the inner
// loop shfl-broadcasts (p,w) while all lanes stream their h column. den accumulated
// lane-local in phase 1, reduced once at the end.
// MODE 0 epilogue: x2 = elu(num/den + b1); h2 = x2@W2 (shfl outer product vs LDS W2);
//                  el2/er2 by shuffle reduction.
// MODE 1 epilogue: out = num/den + b2.
template <int MODE>
__global__ __launch_bounds__(256) void gather_kernel(
    const int* __restrict__ rowptr, const int* __restrict__ deg,
    const int* __restrict__ csr,
    const float* __restrict__ el, const float* __restrict__ er,
    const __hip_bfloat16* __restrict__ h, const float* __restrict__ bias,
    const float* __restrict__ W2, const float* __restrict__ al2,
    const float* __restrict__ ar2,
    __hip_bfloat16* __restrict__ h2, float* __restrict__ el2,
    float* __restrict__ er2, float* __restrict__ out)
{
    const int tid = threadIdx.x;
    float* W2s = nullptr;
    if constexpr (MODE == 0) {
        __shared__ float W2s_[HID * HID];   // 4 KB (allocated only in MODE 0)
        W2s = W2s_;
        ((float4*)W2s)[tid] = ((const float4*)W2)[tid];
        __syncthreads();
    }
    const int node = blockIdx.x * 8 + (tid >> 5);    // grid = N/8 exactly
    const int col = tid & 31;
    const int cnt = deg[node];
    const int start = rowptr[node];
    const float erd = er[node];
    float acc = 0.f, denl = 0.f;
    for (int base = 0; base < cnt; base += 32) {
        const int rem = cnt - base;
        int p = 0; float wv = 0.f;
        if (col < rem) {
            p = csr[start + base + col];
            float sc = el[p >> 7] + erd;
            sc = sc > 0.f ? sc : 0.2f * sc;          // LeakyReLU(0.2)
            wv = __expf(sc);
        }
        denl += wv;
        const int m = rem < 32 ? rem : 32;
        int k = 0;
        for (; k + 3 < m; k += 4) {
            const int   p0 = __shfl(p, k, 32),     p1 = __shfl(p, k + 1, 32);
            const int   p2 = __shfl(p, k + 2, 32), p3 = __shfl(p, k + 3, 32);
            const float w0 = __shfl(wv, k, 32),     w1 = __shfl(wv, k + 1, 32);
            const float w2 = __shfl(wv, k + 2, 32), w3 = __shfl(wv, k + 3, 32);
            const float h0 = __bfloat162float(h[(size_t)(p0 >> 7) * HID + col]);
            const float h1 = __bfloat162float(h[(size_t)(p1 >> 7) * HID + col]);
            const float h2v = __bfloat162float(h[(size_t)(p2 >> 7) * HID + col]);
            const float h3 = __bfloat162float(h[(size_t)(p3 >> 7) * HID + col]);
            acc += w0 * h0 + w1 * h1 + w2 * h2v + w3 * h3;
        }
        for (; k < m; ++k) {
            const int pk = __shfl(p, k, 32);
            const float wk = __shfl(wv, k, 32);
            acc += wk * __bfloat162float(h[(size_t)(pk >> 7) * HID + col]);
        }
    }
    float den = denl;
    #pragma unroll
    for (int mm = 16; mm > 0; mm >>= 1) den += __shfl_xor(den, mm, 32);

    float v = den > 0.f ? acc / den : 0.f;
    v += bias[col];
    if constexpr (MODE == 0) {
        v = v > 0.f ? v : expm1f(v);                 // ELU -> x2 value in this lane
        float hacc = 0.f;
        #pragma unroll
        for (int k = 0; k < HID; ++k)
            hacc += __shfl(v, k, 32) * W2s[k * HID + col];  // h2 = x2 @ W2
        h2[(size_t)node * HID + col] = __float2bfloat16(hacc);
        float pel = hacc * al2[col], per = hacc * ar2[col];
        #pragma unroll
        for (int mm = 16; mm > 0; mm >>= 1) {
            pel += __shfl_xor(pel, mm, 32);
            per += __shfl_xor(per, mm, 32);
        }
        if (col == 0) { el2[node] = pel; er2[node] = per; }
    } else {
        out[(size_t)node * HID + col] = v;
    }
}

extern "C" void kernel_launch(void* const* d_in, const int* in_sizes, int n_in,
                              void* d_out, int out_size, void* d_ws, size_t ws_size,
                              hipStream_t stream) {
    const float* features = (const float*)d_in[0];
    const int*   src      = (const int*)d_in[1];
    const int*   dst      = (const int*)d_in[2];
    const float* W1       = (const float*)d_in[3];
    const float* al1      = (const float*)d_in[4];
    const float* ar1      = (const float*)d_in[5];
    const float* b1       = (const float*)d_in[6];
    const float* W2       = (const float*)d_in[7];
    const float* al2      = (const float*)d_in[8];
    const float* ar2      = (const float*)d_in[9];
    const float* b2       = (const float*)d_in[10];
    float* out = (float*)d_out;

    // Workspace (~29 MB)
    int*  gcur   = (int*)d_ws;                          // 784
    int*  deg    = gcur + 784;                          // 100k
    int*  rowptr = deg + N_NODES;                       // 100k
    int*  pairs  = rowptr + N_NODES;                    // NBUCK*CAP (12.8 MB), sorted in place
    __hip_bfloat16* h1 = (__hip_bfloat16*)(pairs + NBUCK * CAP);  // 6.4 MB
    float* el1 = (float*)(h1 + (size_t)N_NODES * HID);
    float* er1 = el1 + N_NODES;
    __hip_bfloat16* h2 = (__hip_bfloat16*)(er1 + N_NODES);        // 6.4 MB
    float* el2 = (float*)(h2 + (size_t)N_NODES * HID);
    float* er2 = el2 + N_NODES;

    const int NB_E16 = (N_EDGES / 16 + 255) / 256;      // 391
    const int NB_G1  = (N_NODES + 63) / 64;             // 1563

    // Layer-1 GEMM (MFMA) + cursor init
    gemm1_kernel<<<NB_G1, 256, 0, stream>>>(features, W1, al1, ar1,
                                            h1, el1, er1, gcur);
    // Edge binning into fixed bucket regions, then in-LDS bucket sort -> node CSR
    bin_kernel<<<NB_E16, 256, 0, stream>>>(src, dst, gcur, pairs);
    lsort_kernel<<<NBUCK, 256, 0, stream>>>(gcur, pairs, deg, rowptr);
    // Layer-1 aggregate + ELU + fused layer-2 GEMM -> h2, el2, er2
    gather_kernel<0><<<N_NODES / 8, 256, 0, stream>>>(rowptr, deg, pairs,
                                                      el1, er1, h1, b1,
                                                      W2, al2, ar2,
                                                      h2, el2, er2, nullptr);
    // Layer-2 aggregate -> out = num/den + b2
    gather_kernel<1><<<N_NODES / 8, 256, 0, stream>>>(rowptr, deg, pairs,
                                                      el2, er2, h2, b2,
                                                      nullptr, nullptr, nullptr,
                                                      nullptr, nullptr, nullptr, out);
}